// Round 9
// baseline (583.079 us; speedup 1.0000x reference)
//
#include <hip/hip_runtime.h>

typedef __bf16 bf16x8 __attribute__((ext_vector_type(8)));
typedef float f32x4 __attribute__((ext_vector_type(4)));

#define DFEAT 128
#define HDIM 64
#define IDX_BITS 21
#define IDX_MASK ((1u << IDX_BITS) - 1)
#define EMPTY_SLOT 0xFFFFFFFFFFFFFFFFull

// fast shifted-softplus: log(1+e^x) - log2, via native v_exp_f32/v_log_f32
__device__ __forceinline__ float ssp_fast(float x) {
    float m = fmaxf(x, 0.0f);
    float t = __expf(-fabsf(x));
    return m + __logf(1.0f + t) - 0.69314718055994531f;
}

// edge_index may arrive as int32 (harness contract) or int64 (reference dtype).
// Detect at runtime: int64 layout has all-zero odd dwords (values < 2^31).
__global__ void detect_idx_kernel(const unsigned int* __restrict__ p, int n_check,
                                  unsigned int* __restrict__ flag_any) {
    unsigned int acc = 0;
    for (int i = threadIdx.x; i < n_check; i += blockDim.x)
        acc |= p[2 * i + 1];
    if (acc) atomicOr(flag_any, 1u);
}

__device__ __forceinline__ int load_idx(const void* p, int is64, long long i) {
    if (is64) return (int)((const long long*)p)[i];
    return ((const int*)p)[i];
}

// bf16 convert of 8 floats from two float4s — member access only, no casts.
#define CVT8H(P, Q, H) do { \
    H[0] = (__bf16)P.x; H[1] = (__bf16)P.y; H[2] = (__bf16)P.z; H[3] = (__bf16)P.w; \
    H[4] = (__bf16)Q.x; H[5] = (__bf16)Q.y; H[6] = (__bf16)Q.z; H[7] = (__bf16)Q.w; \
} while (0)

#define MF(A, B, C) __builtin_amdgcn_mfma_f32_16x16x32_bf16(A, B, C, 0, 0, 0)

// One K-chunk (32 of 128): convert A, 1 MFMA per N-tile (pure bf16; absmax
// 0.031 vs 0.1406 threshold measured in round 6).
#define KSTEP(P, Q, KT) do { \
    bf16x8 h, bh; \
    CVT8H(P, Q, h); \
    bh = hiTab[((KT)*4 + 0) * 64 + lane]; acc0 = MF(h, bh, acc0); \
    bh = hiTab[((KT)*4 + 1) * 64 + lane]; acc1 = MF(h, bh, acc1); \
    bh = hiTab[((KT)*4 + 2) * 64 + lane]; acc2 = MF(h, bh, acc2); \
    bh = hiTab[((KT)*4 + 3) * 64 + lane]; acc3 = MF(h, bh, acc3); \
} while (0)

// row-slice ssp + w2 dot + 16-lane reduce for C-row j (compile-time J).
#define REDJ(J, OUT) do { \
    float z0 = acc0[J] + b1v0, z1 = acc1[J] + b1v1; \
    float z2 = acc2[J] + b1v2, z3 = acc3[J] + b1v3; \
    float t = ssp_fast(z0) * w2v0 + ssp_fast(z1) * w2v1 \
            + ssp_fast(z2) * w2v2 + ssp_fast(z3) * w2v3; \
    t += __shfl_xor(t, 1); t += __shfl_xor(t, 2); \
    t += __shfl_xor(t, 4); t += __shfl_xor(t, 8); \
    OUT = t; \
} while (0)

// Kernel A: per-edge MLP via bf16 MFMA — EXACT round-6 version (passed,
// absmax 0.03125). All per-tile state in NAMED registers (rule #20).
// W1 bf16 fragment table in 16 KB LDS. No fused bias (round 7/8's fused
// epilogue scan was implicated in a deterministic absmax-2.44 failure —
// divergent-branch __shfl reading inactive lanes is UB on HIP).
__global__ __launch_bounds__(256, 4) void mlp_mag_kernel(
    const float* __restrict__ feats,
    const float* __restrict__ w1,
    const float* __restrict__ b1,
    const float* __restrict__ w2,
    const float* __restrict__ b2,
    float* __restrict__ mag_raw,
    int E)
{
    __shared__ __align__(16) unsigned char smem[32768];
    float* w1s = (float*)smem;                 // transient: raw w1 (32 KB)
    bf16x8* hiTab = (bf16x8*)smem;             // final: bf16 frags (16 KB)

    const int lane = threadIdx.x & 63;
    const int r = lane & 15;
    const int g = lane >> 4;
    const int wave = blockIdx.x * (blockDim.x >> 6) + (threadIdx.x >> 6);
    const int nwaves = gridDim.x * (blockDim.x >> 6);

    // Stage B fragment table in LDS (once per block).
    for (int idx = threadIdx.x; idx < DFEAT * HDIM / 4; idx += blockDim.x)
        ((float4*)w1s)[idx] = ((const float4*)w1)[idx];
    __syncthreads();
    {
        const int tkt = threadIdx.x >> 6;      // this thread builds frags for k-chunk tkt
        const int tl = threadIdx.x & 63;
        const int tg = tl >> 4, tr = tl & 15;
        float vals[4][8];
#pragma unroll
        for (int nt = 0; nt < 4; ++nt)
#pragma unroll
            for (int i = 0; i < 8; ++i)
                vals[nt][i] = w1s[(tkt * 32 + tg * 8 + i) * HDIM + nt * 16 + tr];
        __syncthreads();                        // done reading raw w1; safe to overwrite
#pragma unroll
        for (int nt = 0; nt < 4; ++nt) {
            bf16x8 h;
#pragma unroll
            for (int i = 0; i < 8; ++i) h[i] = (__bf16)vals[nt][i];
            hiTab[(tkt * 4 + nt) * 64 + tl] = h;
        }
        __syncthreads();
    }

    const float b1v0 = b1[0 * 16 + r], b1v1 = b1[1 * 16 + r];
    const float b1v2 = b1[2 * 16 + r], b1v3 = b1[3 * 16 + r];
    const float w2v0 = w2[0 * 16 + r], w2v1 = w2[1 * 16 + r];
    const float w2v2 = w2[2 * 16 + r], w2v3 = w2[3 * 16 + r];
    const float b2v = b2[0];

    const int ntiles = (E + 15) >> 4;
    for (int tile = wave; tile < ntiles; tile += nwaves) {
        const int e0 = tile << 4;
        int er = e0 + r;
        if (er >= E) er = E - 1;           // clamp: loads stay valid; store is guarded

        const float4* fp = (const float4*)(feats + (size_t)er * DFEAT) + g * 2;
        float4 p0 = fp[0],  p1 = fp[1];
        float4 p2 = fp[8],  p3 = fp[9];
        float4 p4 = fp[16], p5 = fp[17];
        float4 p6 = fp[24], p7 = fp[25];

        f32x4 acc0 = {0.f,0.f,0.f,0.f}, acc1 = {0.f,0.f,0.f,0.f};
        f32x4 acc2 = {0.f,0.f,0.f,0.f}, acc3 = {0.f,0.f,0.f,0.f};
        KSTEP(p0, p1, 0);
        KSTEP(p2, p3, 1);
        KSTEP(p4, p5, 2);
        KSTEP(p6, p7, 3);

        float s0, s1, s2, s3;
        REDJ(0, s0); REDJ(1, s1); REDJ(2, s2); REDJ(3, s3);

        if (r < 4) {
            int e = e0 + g * 4 + r;
            if (e < E) {
                // 4-way select by r without a runtime-indexed array (cndmask chain)
                float sel = (r == 0) ? s0 : (r == 1) ? s1 : (r == 2) ? s2 : s3;
                mag_raw[e] = sel + b2v;
            }
        }
    }
}

// Kernel B: scatter-mean inputs via sorted-run segmented reduction — EXACT
// round-6 version (passed). ~2 atomics per center-run; correct if unsorted.
__global__ __launch_bounds__(256) void bias_kernel(
    const void* __restrict__ eidx,
    const float* __restrict__ mag,
    float* __restrict__ csum,
    float* __restrict__ ccnt,
    const unsigned int* __restrict__ flag_any,
    int E)
{
    __shared__ int cs[256];
    __shared__ float ms[256];
    const int is64 = (flag_any[0] == 0u) ? 1 : 0;
    const int tloc = threadIdx.x;
    const int i = blockIdx.x * 256 + tloc;
    int c = -1; float m = 0.0f;
    if (i < E) { c = load_idx(eidx, is64, i); m = mag[i]; }
    cs[tloc] = c; ms[tloc] = m;
    __syncthreads();
    if (i < E) {
        bool leader = (tloc == 0) || (cs[tloc - 1] != c);
        if (leader) {
            float s = 0.0f; int n = 0; int j = tloc;
            int lim = min(256, E - blockIdx.x * 256);
            while (j < lim && cs[j] == c) { s += ms[j]; ++n; ++j; }
            atomicAdd(&csum[c], s);
            atomicAdd(&ccnt[c], (float)n);
        }
    }
}

// Kernel C: hash-join pairing (replaces argsort) + fused debias + force.
// KEY EXACTNESS INVARIANT: key arithmetic is BITWISE identical to the
// reference (f32 division vec/l, fabs, (x+y)+z, 1e10f mult, trunc) — the
// dataset's no-collision guarantee is defined w.r.t. reference keys.
// The two directed copies of an undirected edge have vec[j] == -vec[i] and
// len[j] == len[i] bitwise (f64 norm of +-v), so keys match exactly and the
// partner's unit vector is EXACTLY -u: the finisher emits both edges' force
// contributions (+f to out[ci], -f to out[cj]) with no partner vec/len loads.
// Race-free: both partners walk the same probe sequence; slots never empty.
__global__ __launch_bounds__(256) void pair_force_kernel(
    const float* __restrict__ vec,
    const float* __restrict__ len,
    const void* __restrict__ eidx,
    const float* __restrict__ mag,
    const float* __restrict__ csum,
    const float* __restrict__ ccnt,
    unsigned long long* __restrict__ tab,
    float* __restrict__ out,
    const unsigned int* __restrict__ flag_any,
    int E, int hash_bits)
{
    int i = blockIdx.x * blockDim.x + threadIdx.x;
    if (i >= E) return;
    const int is64 = (flag_any[0] == 0u) ? 1 : 0;

    float l = len[i];
    float ux = vec[3 * i + 0] / l;     // IEEE division — matches reference bitwise
    float uy = vec[3 * i + 1] / l;
    float uz = vec[3 * i + 2] / l;
    float s3 = (fabsf(ux) + fabsf(uy)) + fabsf(uz);

    int ci_ = load_idx(eidx, is64, i);
    int ni_ = load_idx(eidx, is64, (long long)E + i);

    long long key = (long long)ci_ + (long long)ni_
                  + (long long)(1.0e10f * l)
                  + (long long)(1.0e10f * s3);

    unsigned long long entry = ((unsigned long long)key << IDX_BITS) | (unsigned)i;
    unsigned long long h = (unsigned long long)key * 0x9E3779B97F4A7C15ull;
    unsigned slot = (unsigned)(h >> (64 - hash_bits));
    const unsigned smask = (1u << hash_bits) - 1u;

    int j;
    while (true) {
        unsigned long long old = atomicCAS(&tab[slot], EMPTY_SLOT, entry);
        if (old == EMPTY_SLOT) return;  // first arrival: partner finishes the job
        if ((old >> IDX_BITS) == (unsigned long long)key) {
            j = (int)(old & IDX_MASK);
            break;
        }
        slot = (slot + 1) & smask;
    }

    int cj_ = load_idx(eidx, is64, j);
    float bi = csum[ci_] / fmaxf(ccnt[ci_], 1.0f);
    float bj = csum[cj_] / fmaxf(ccnt[cj_], 1.0f);
    float avg = 0.5f * ((mag[i] - bi) + (mag[j] - bj));

    float fx = avg * ux, fy = avg * uy, fz = avg * uz;
    atomicAdd(&out[ci_ * 3 + 0], fx);
    atomicAdd(&out[ci_ * 3 + 1], fy);
    atomicAdd(&out[ci_ * 3 + 2], fz);
    atomicAdd(&out[cj_ * 3 + 0], -fx);   // partner unit vector is exactly -u
    atomicAdd(&out[cj_ * 3 + 1], -fy);
    atomicAdd(&out[cj_ * 3 + 2], -fz);
}

extern "C" void kernel_launch(void* const* d_in, const int* in_sizes, int n_in,
                              void* d_out, int out_size, void* d_ws, size_t ws_size,
                              hipStream_t stream) {
    const float* feats = (const float*)d_in[0];
    const float* vec   = (const float*)d_in[1];
    const float* len   = (const float*)d_in[2];
    const void*  eidx  = d_in[3];
    const float* w1 = (const float*)d_in[4];
    const float* b1 = (const float*)d_in[5];
    const float* w2 = (const float*)d_in[6];
    const float* b2 = (const float*)d_in[7];
    float* out = (float*)d_out;

    const int E = in_sizes[0] / DFEAT;
    const int N = out_size / 3;

    // Workspace: mag (E f32) | csum (N) | ccnt (N) | flag (256B) | tab
    char* ws = (char*)d_ws;
    size_t off_mag  = 0;
    size_t off_csum = (off_mag + (size_t)E * 4 + 255) & ~(size_t)255;
    size_t off_ccnt = off_csum + (size_t)N * 4;
    size_t off_flag = (off_ccnt + (size_t)N * 4 + 255) & ~(size_t)255;
    size_t off_tab  = off_flag + 256;

    float* mag     = (float*)(ws + off_mag);
    float* csum    = (float*)(ws + off_csum);
    float* ccnt    = (float*)(ws + off_ccnt);
    unsigned int* flag_any = (unsigned int*)(ws + off_flag);

    int hash_bits = 21;
    while (hash_bits > 20 && off_tab + (8ull << hash_bits) > ws_size) --hash_bits;
    unsigned long long* tab = (unsigned long long*)(ws + off_tab);

    // one contiguous memset covers csum | ccnt | flag
    hipMemsetAsync(csum, 0, off_flag + 256 - off_csum, stream);
    hipMemsetAsync(tab, 0xFF, (size_t)8 << hash_bits, stream);
    hipMemsetAsync(out, 0, (size_t)out_size * 4, stream);

    int n_check = E < 1024 ? E : 1024;
    detect_idx_kernel<<<1, 256, 0, stream>>>((const unsigned int*)eidx, n_check, flag_any);

    mlp_mag_kernel<<<1024, 256, 0, stream>>>(feats, w1, b1, w2, b2, mag, E);

    int eblocks = (E + 255) / 256;
    bias_kernel<<<eblocks, 256, 0, stream>>>(eidx, mag, csum, ccnt, flag_any, E);
    pair_force_kernel<<<eblocks, 256, 0, stream>>>(vec, len, eidx, mag, csum, ccnt,
                                                   tab, out, flag_any, E, hash_bits);
}

// Round 10
// 435.052 us; speedup vs baseline: 1.3402x; 1.3402x over previous
//
#include <hip/hip_runtime.h>

typedef __bf16 bf16x8 __attribute__((ext_vector_type(8)));
typedef float f32x4 __attribute__((ext_vector_type(4)));

#define DFEAT 128
#define HDIM 64
#define IDX_BITS 21
#define IDX_MASK ((1u << IDX_BITS) - 1)
#define EMPTY_SLOT 0xFFFFFFFFFFFFFFFFull

// fast shifted-softplus: log(1+e^x) - log2, via native v_exp_f32/v_log_f32
__device__ __forceinline__ float ssp_fast(float x) {
    float m = fmaxf(x, 0.0f);
    float t = __expf(-fabsf(x));
    return m + __logf(1.0f + t) - 0.69314718055994531f;
}

// edge_index may arrive as int32 (harness contract) or int64 (reference dtype).
// Detect at runtime: int64 layout has all-zero odd dwords (values < 2^31).
__global__ void detect_idx_kernel(const unsigned int* __restrict__ p, int n_check,
                                  unsigned int* __restrict__ flag_any) {
    unsigned int acc = 0;
    for (int i = threadIdx.x; i < n_check; i += blockDim.x)
        acc |= p[2 * i + 1];
    if (acc) atomicOr(flag_any, 1u);
}

__device__ __forceinline__ int load_idx(const void* p, int is64, long long i) {
    if (is64) return (int)((const long long*)p)[i];
    return ((const int*)p)[i];
}

// bf16 convert of 8 floats from two float4s — member access only, no casts.
#define CVT8H(P, Q, H) do { \
    H[0] = (__bf16)P.x; H[1] = (__bf16)P.y; H[2] = (__bf16)P.z; H[3] = (__bf16)P.w; \
    H[4] = (__bf16)Q.x; H[5] = (__bf16)Q.y; H[6] = (__bf16)Q.z; H[7] = (__bf16)Q.w; \
} while (0)

#define MF(A, B, C) __builtin_amdgcn_mfma_f32_16x16x32_bf16(A, B, C, 0, 0, 0)

// One K-chunk (32 of 128): convert A, 1 MFMA per N-tile (pure bf16; absmax
// 0.031 vs 0.1406 threshold, measured rounds 6/9).
#define KSTEP(P, Q, KT) do { \
    bf16x8 h, bh; \
    CVT8H(P, Q, h); \
    bh = hiTab[((KT)*4 + 0) * 64 + lane]; acc0 = MF(h, bh, acc0); \
    bh = hiTab[((KT)*4 + 1) * 64 + lane]; acc1 = MF(h, bh, acc1); \
    bh = hiTab[((KT)*4 + 2) * 64 + lane]; acc2 = MF(h, bh, acc2); \
    bh = hiTab[((KT)*4 + 3) * 64 + lane]; acc3 = MF(h, bh, acc3); \
} while (0)

// row-slice ssp + w2 dot + 16-lane reduce for C-row j (compile-time J).
#define REDJ(J, OUT) do { \
    float z0 = acc0[J] + b1v0, z1 = acc1[J] + b1v1; \
    float z2 = acc2[J] + b1v2, z3 = acc3[J] + b1v3; \
    float t = ssp_fast(z0) * w2v0 + ssp_fast(z1) * w2v1 \
            + ssp_fast(z2) * w2v2 + ssp_fast(z3) * w2v3; \
    t += __shfl_xor(t, 1); t += __shfl_xor(t, 2); \
    t += __shfl_xor(t, 4); t += __shfl_xor(t, 8); \
    OUT = t; \
} while (0)

// Kernel A: per-edge MLP via bf16 MFMA (round-6 structure, proven).
// Occupancy fix: W1 fragments built DIRECTLY from global (one-time, L2-hit)
// so LDS is only 16 KB, and __launch_bounds__(256,6) -> 6 blocks/CU,
// 24 waves/CU (was 16) to raise in-flight HBM bytes (latency-bound before).
__global__ __launch_bounds__(256, 6) void mlp_mag_kernel(
    const float* __restrict__ feats,
    const float* __restrict__ w1,
    const float* __restrict__ b1,
    const float* __restrict__ w2,
    const float* __restrict__ b2,
    float* __restrict__ mag_raw,
    int E)
{
    __shared__ __align__(16) bf16x8 hiTab[1024];   // 16 KB: W1 bf16 fragments

    const int lane = threadIdx.x & 63;
    const int r = lane & 15;
    const int g = lane >> 4;
    const int wave = blockIdx.x * (blockDim.x >> 6) + (threadIdx.x >> 6);
    const int nwaves = gridDim.x * (blockDim.x >> 6);

    // Build B fragment table straight from global w1 (32 scalar reads/thread,
    // 64B-segment locality, L2-resident after the first blocks).
    {
        const int tkt = threadIdx.x >> 6;      // this thread builds frags for k-chunk tkt
        const int tl = threadIdx.x & 63;
        const int tg = tl >> 4, tr = tl & 15;
#pragma unroll
        for (int nt = 0; nt < 4; ++nt) {
            bf16x8 h;
#pragma unroll
            for (int i = 0; i < 8; ++i)
                h[i] = (__bf16)w1[(tkt * 32 + tg * 8 + i) * HDIM + nt * 16 + tr];
            hiTab[(tkt * 4 + nt) * 64 + tl] = h;
        }
        __syncthreads();
    }

    const float b1v0 = b1[0 * 16 + r], b1v1 = b1[1 * 16 + r];
    const float b1v2 = b1[2 * 16 + r], b1v3 = b1[3 * 16 + r];
    const float w2v0 = w2[0 * 16 + r], w2v1 = w2[1 * 16 + r];
    const float w2v2 = w2[2 * 16 + r], w2v3 = w2[3 * 16 + r];
    const float b2v = b2[0];

    const int ntiles = (E + 15) >> 4;
    for (int tile = wave; tile < ntiles; tile += nwaves) {
        const int e0 = tile << 4;
        int er = e0 + r;
        if (er >= E) er = E - 1;           // clamp: loads stay valid; store is guarded

        const float4* fp = (const float4*)(feats + (size_t)er * DFEAT) + g * 2;
        float4 p0 = fp[0],  p1 = fp[1];
        float4 p2 = fp[8],  p3 = fp[9];
        float4 p4 = fp[16], p5 = fp[17];
        float4 p6 = fp[24], p7 = fp[25];

        f32x4 acc0 = {0.f,0.f,0.f,0.f}, acc1 = {0.f,0.f,0.f,0.f};
        f32x4 acc2 = {0.f,0.f,0.f,0.f}, acc3 = {0.f,0.f,0.f,0.f};
        KSTEP(p0, p1, 0);
        KSTEP(p2, p3, 1);
        KSTEP(p4, p5, 2);
        KSTEP(p6, p7, 3);

        float s0, s1, s2, s3;
        REDJ(0, s0); REDJ(1, s1); REDJ(2, s2); REDJ(3, s3);

        if (r < 4) {
            int e = e0 + g * 4 + r;
            if (e < E) {
                // 4-way select by r without a runtime-indexed array (cndmask chain)
                float sel = (r == 0) ? s0 : (r == 1) ? s1 : (r == 2) ? s2 : s3;
                mag_raw[e] = sel + b2v;
            }
        }
    }
}

// Kernel B: scatter-mean inputs via sorted-run segmented reduction — round-6
// version (proven). ~2 atomics per center-run; correct even if unsorted.
__global__ __launch_bounds__(256) void bias_kernel(
    const void* __restrict__ eidx,
    const float* __restrict__ mag,
    float* __restrict__ csum,
    float* __restrict__ ccnt,
    const unsigned int* __restrict__ flag_any,
    int E)
{
    __shared__ int cs[256];
    __shared__ float ms[256];
    const int is64 = (flag_any[0] == 0u) ? 1 : 0;
    const int tloc = threadIdx.x;
    const int i = blockIdx.x * 256 + tloc;
    int c = -1; float m = 0.0f;
    if (i < E) { c = load_idx(eidx, is64, i); m = mag[i]; }
    cs[tloc] = c; ms[tloc] = m;
    __syncthreads();
    if (i < E) {
        bool leader = (tloc == 0) || (cs[tloc - 1] != c);
        if (leader) {
            float s = 0.0f; int n = 0; int j = tloc;
            int lim = min(256, E - blockIdx.x * 256);
            while (j < lim && cs[j] == c) { s += ms[j]; ++n; ++j; }
            atomicAdd(&csum[c], s);
            atomicAdd(&ccnt[c], (float)n);
        }
    }
}

// Kernel C: hash-join pairing (replaces argsort) — round-6 version (proven).
// KEY EXACTNESS INVARIANT: key arithmetic is BITWISE identical to the
// reference (f32 division vec/l, fabs, (x+y)+z, 1e10f mult, trunc).
// Finisher debiases both pair members, averages, writes avg IN PLACE into mag
// (each edge's slot touched only by its own pair's finisher). No out atomics
// here — round 9 proved 6 scattered atomics/finisher costs ~250 us extra.
__global__ __launch_bounds__(256) void pair_kernel(
    const float* __restrict__ vec,
    const float* __restrict__ len,
    const void* __restrict__ eidx,
    float* __restrict__ mag,
    const float* __restrict__ csum,
    const float* __restrict__ ccnt,
    unsigned long long* __restrict__ tab,
    const unsigned int* __restrict__ flag_any,
    int E, int hash_bits)
{
    int i = blockIdx.x * blockDim.x + threadIdx.x;
    if (i >= E) return;
    const int is64 = (flag_any[0] == 0u) ? 1 : 0;

    float l = len[i];
    float ux = vec[3 * i + 0] / l;     // IEEE division — matches reference bitwise
    float uy = vec[3 * i + 1] / l;
    float uz = vec[3 * i + 2] / l;
    float s3 = (fabsf(ux) + fabsf(uy)) + fabsf(uz);

    int ci_ = load_idx(eidx, is64, i);
    int ni_ = load_idx(eidx, is64, (long long)E + i);

    long long key = (long long)ci_ + (long long)ni_
                  + (long long)(1.0e10f * l)
                  + (long long)(1.0e10f * s3);

    unsigned long long entry = ((unsigned long long)key << IDX_BITS) | (unsigned)i;
    unsigned long long h = (unsigned long long)key * 0x9E3779B97F4A7C15ull;
    unsigned slot = (unsigned)(h >> (64 - hash_bits));
    const unsigned smask = (1u << hash_bits) - 1u;

    int j;
    while (true) {
        unsigned long long old = atomicCAS(&tab[slot], EMPTY_SLOT, entry);
        if (old == EMPTY_SLOT) return;  // first arrival: partner finishes the job
        if ((old >> IDX_BITS) == (unsigned long long)key) {
            j = (int)(old & IDX_MASK);
            break;
        }
        slot = (slot + 1) & smask;
    }

    int cj_ = load_idx(eidx, is64, j);
    float mi = mag[i] - csum[ci_] / fmaxf(ccnt[ci_], 1.0f);
    float mj = mag[j] - csum[cj_] / fmaxf(ccnt[cj_], 1.0f);
    float avg = 0.5f * (mi + mj);
    mag[i] = avg;
    mag[j] = avg;
}

// Kernel D: edge_force = mag*unit, segment-sum by (sorted) center via run
// detection; ~3 atomics per run instead of 3 per edge — round-6 version.
__global__ __launch_bounds__(256) void force_kernel(
    const float* __restrict__ vec,
    const float* __restrict__ len,
    const void* __restrict__ eidx,
    const float* __restrict__ mag,
    float* __restrict__ out,
    const unsigned int* __restrict__ flag_any,
    int E)
{
    __shared__ int cs[256];
    __shared__ float fx[256], fy[256], fz[256];
    const int is64 = (flag_any[0] == 0u) ? 1 : 0;
    const int tloc = threadIdx.x;
    const int i = blockIdx.x * 256 + tloc;
    int c = -1;
    if (i < E) {
        c = load_idx(eidx, is64, i);
        float l = len[i];
        float m = mag[i];
        fx[tloc] = m * vec[3 * i + 0] / l;
        fy[tloc] = m * vec[3 * i + 1] / l;
        fz[tloc] = m * vec[3 * i + 2] / l;
    }
    cs[tloc] = c;
    __syncthreads();
    if (i < E) {
        bool leader = (tloc == 0) || (cs[tloc - 1] != c);
        if (leader) {
            float sx = 0.f, sy = 0.f, sz = 0.f;
            int j = tloc;
            int lim = min(256, E - blockIdx.x * 256);
            while (j < lim && cs[j] == c) { sx += fx[j]; sy += fy[j]; sz += fz[j]; ++j; }
            atomicAdd(&out[c * 3 + 0], sx);
            atomicAdd(&out[c * 3 + 1], sy);
            atomicAdd(&out[c * 3 + 2], sz);
        }
    }
}

extern "C" void kernel_launch(void* const* d_in, const int* in_sizes, int n_in,
                              void* d_out, int out_size, void* d_ws, size_t ws_size,
                              hipStream_t stream) {
    const float* feats = (const float*)d_in[0];
    const float* vec   = (const float*)d_in[1];
    const float* len   = (const float*)d_in[2];
    const void*  eidx  = d_in[3];
    const float* w1 = (const float*)d_in[4];
    const float* b1 = (const float*)d_in[5];
    const float* w2 = (const float*)d_in[6];
    const float* b2 = (const float*)d_in[7];
    float* out = (float*)d_out;

    const int E = in_sizes[0] / DFEAT;
    const int N = out_size / 3;

    // Workspace: mag (E f32) | csum (N) | ccnt (N) | flag (256B) | tab
    char* ws = (char*)d_ws;
    size_t off_mag  = 0;
    size_t off_csum = (off_mag + (size_t)E * 4 + 255) & ~(size_t)255;
    size_t off_ccnt = off_csum + (size_t)N * 4;
    size_t off_flag = (off_ccnt + (size_t)N * 4 + 255) & ~(size_t)255;
    size_t off_tab  = off_flag + 256;

    float* mag     = (float*)(ws + off_mag);
    float* csum    = (float*)(ws + off_csum);
    float* ccnt    = (float*)(ws + off_ccnt);
    unsigned int* flag_any = (unsigned int*)(ws + off_flag);

    int hash_bits = 21;
    while (hash_bits > 20 && off_tab + (8ull << hash_bits) > ws_size) --hash_bits;
    unsigned long long* tab = (unsigned long long*)(ws + off_tab);

    // one contiguous memset covers csum | ccnt | flag
    hipMemsetAsync(csum, 0, off_flag + 256 - off_csum, stream);
    hipMemsetAsync(tab, 0xFF, (size_t)8 << hash_bits, stream);
    hipMemsetAsync(out, 0, (size_t)out_size * 4, stream);

    int n_check = E < 1024 ? E : 1024;
    detect_idx_kernel<<<1, 256, 0, stream>>>((const unsigned int*)eidx, n_check, flag_any);

    mlp_mag_kernel<<<1536, 256, 0, stream>>>(feats, w1, b1, w2, b2, mag, E);

    int eblocks = (E + 255) / 256;
    bias_kernel<<<eblocks, 256, 0, stream>>>(eidx, mag, csum, ccnt, flag_any, E);
    pair_kernel<<<eblocks, 256, 0, stream>>>(vec, len, eidx, mag, csum, ccnt,
                                             tab, flag_any, E, hash_bits);
    force_kernel<<<eblocks, 256, 0, stream>>>(vec, len, eidx, mag, out, flag_any, E);
}

// Round 11
// 336.938 us; speedup vs baseline: 1.7305x; 1.2912x over previous
//
#include <hip/hip_runtime.h>

typedef __bf16 bf16x8 __attribute__((ext_vector_type(8)));
typedef float f32x4 __attribute__((ext_vector_type(4)));

#define DFEAT 128
#define HDIM 64
#define IDX_BITS 21
#define IDX_MASK ((1u << IDX_BITS) - 1)
#define EMPTY_SLOT 0xFFFFFFFFFFFFFFFFull

// fast shifted-softplus: log(1+e^x) - log2, via native v_exp_f32/v_log_f32
__device__ __forceinline__ float ssp_fast(float x) {
    float m = fmaxf(x, 0.0f);
    float t = __expf(-fabsf(x));
    return m + __logf(1.0f + t) - 0.69314718055994531f;
}

// edge_index may arrive as int32 (harness contract) or int64 (reference dtype).
// Detect at runtime: int64 layout has all-zero odd dwords (values < 2^31).
__global__ void detect_idx_kernel(const unsigned int* __restrict__ p, int n_check,
                                  unsigned int* __restrict__ flag_any) {
    unsigned int acc = 0;
    for (int i = threadIdx.x; i < n_check; i += blockDim.x)
        acc |= p[2 * i + 1];
    if (acc) atomicOr(flag_any, 1u);
}

__device__ __forceinline__ int load_idx(const void* p, int is64, long long i) {
    if (is64) return (int)((const long long*)p)[i];
    return ((const int*)p)[i];
}

// bf16 convert of 8 floats from two float4s — member access only, no casts.
#define CVT8H(P, Q, H) do { \
    H[0] = (__bf16)P.x; H[1] = (__bf16)P.y; H[2] = (__bf16)P.z; H[3] = (__bf16)P.w; \
    H[4] = (__bf16)Q.x; H[5] = (__bf16)Q.y; H[6] = (__bf16)Q.z; H[7] = (__bf16)Q.w; \
} while (0)

#define MF(A, B, C) __builtin_amdgcn_mfma_f32_16x16x32_bf16(A, B, C, 0, 0, 0)

// One K-chunk (32 of 128): convert A, 1 MFMA per N-tile (pure bf16; absmax
// 0.031 vs 0.1406 threshold, measured rounds 6/9/10).
#define KSTEP(P, Q, KT, A0, A1, A2, A3) do { \
    bf16x8 h, bh; \
    CVT8H(P, Q, h); \
    bh = hiTab[((KT)*4 + 0) * 64 + lane]; A0 = MF(h, bh, A0); \
    bh = hiTab[((KT)*4 + 1) * 64 + lane]; A1 = MF(h, bh, A1); \
    bh = hiTab[((KT)*4 + 2) * 64 + lane]; A2 = MF(h, bh, A2); \
    bh = hiTab[((KT)*4 + 3) * 64 + lane]; A3 = MF(h, bh, A3); \
} while (0)

// row-slice ssp + w2 dot + 16-lane reduce for C-row j (compile-time J).
#define REDJ(J, OUT, A0, A1, A2, A3) do { \
    float z0 = A0[J] + b1v0, z1 = A1[J] + b1v1; \
    float z2 = A2[J] + b1v2, z3 = A3[J] + b1v3; \
    float t = ssp_fast(z0) * w2v0 + ssp_fast(z1) * w2v1 \
            + ssp_fast(z2) * w2v2 + ssp_fast(z3) * w2v3; \
    t += __shfl_xor(t, 1); t += __shfl_xor(t, 2); \
    t += __shfl_xor(t, 4); t += __shfl_xor(t, 8); \
    OUT = t; \
} while (0)

// Compute + store one 16-edge tile from preloaded p0..p7 (named regs).
#define TILE_COMPUTE(P0,P1,P2,P3,P4,P5,P6,P7, E0) do { \
    f32x4 c0 = {0.f,0.f,0.f,0.f}, c1 = {0.f,0.f,0.f,0.f}; \
    f32x4 c2 = {0.f,0.f,0.f,0.f}, c3 = {0.f,0.f,0.f,0.f}; \
    KSTEP(P0, P1, 0, c0, c1, c2, c3); \
    KSTEP(P2, P3, 1, c0, c1, c2, c3); \
    KSTEP(P4, P5, 2, c0, c1, c2, c3); \
    KSTEP(P6, P7, 3, c0, c1, c2, c3); \
    float s0, s1, s2, s3; \
    REDJ(0, s0, c0, c1, c2, c3); REDJ(1, s1, c0, c1, c2, c3); \
    REDJ(2, s2, c0, c1, c2, c3); REDJ(3, s3, c0, c1, c2, c3); \
    if (r < 4) { \
        int e = (E0) + g * 4 + r; \
        if (e < E) { \
            float sel = (r == 0) ? s0 : (r == 1) ? s1 : (r == 2) ? s2 : s3; \
            mag_raw[e] = sel + b2v; \
        } \
    } \
} while (0)

// Kernel A: per-edge MLP via bf16 MFMA (round-6 structure, proven 190 us) +
// TWO tiles per wave-iteration: all 16 float4 loads issue before tile-A
// compute, so tile-B's HBM latency hides under A's ~600-cycle MFMA+epilogue.
// Round 10 proved latency hiding here comes from per-wave ILP, not wave count
// (VGPR cap 85 -> serialized loads -> +100 us). Keep cap at 128 (4 waves/EU).
__global__ __launch_bounds__(256, 4) void mlp_mag_kernel(
    const float* __restrict__ feats,
    const float* __restrict__ w1,
    const float* __restrict__ b1,
    const float* __restrict__ w2,
    const float* __restrict__ b2,
    float* __restrict__ mag_raw,
    int E)
{
    __shared__ __align__(16) unsigned char smem[32768];
    float* w1s = (float*)smem;                 // transient: raw w1 (32 KB)
    bf16x8* hiTab = (bf16x8*)smem;             // final: bf16 frags (16 KB)

    const int lane = threadIdx.x & 63;
    const int r = lane & 15;
    const int g = lane >> 4;
    const int wave = blockIdx.x * (blockDim.x >> 6) + (threadIdx.x >> 6);
    const int nwaves = gridDim.x * (blockDim.x >> 6);

    // Stage B fragment table in LDS (once per block).
    for (int idx = threadIdx.x; idx < DFEAT * HDIM / 4; idx += blockDim.x)
        ((float4*)w1s)[idx] = ((const float4*)w1)[idx];
    __syncthreads();
    {
        const int tkt = threadIdx.x >> 6;      // this thread builds frags for k-chunk tkt
        const int tl = threadIdx.x & 63;
        const int tg = tl >> 4, tr = tl & 15;
        float vals[4][8];
#pragma unroll
        for (int nt = 0; nt < 4; ++nt)
#pragma unroll
            for (int i = 0; i < 8; ++i)
                vals[nt][i] = w1s[(tkt * 32 + tg * 8 + i) * HDIM + nt * 16 + tr];
        __syncthreads();                        // done reading raw w1; safe to overwrite
#pragma unroll
        for (int nt = 0; nt < 4; ++nt) {
            bf16x8 h;
#pragma unroll
            for (int i = 0; i < 8; ++i) h[i] = (__bf16)vals[nt][i];
            hiTab[(tkt * 4 + nt) * 64 + tl] = h;
        }
        __syncthreads();
    }

    const float b1v0 = b1[0 * 16 + r], b1v1 = b1[1 * 16 + r];
    const float b1v2 = b1[2 * 16 + r], b1v3 = b1[3 * 16 + r];
    const float w2v0 = w2[0 * 16 + r], w2v1 = w2[1 * 16 + r];
    const float w2v2 = w2[2 * 16 + r], w2v3 = w2[3 * 16 + r];
    const float b2v = b2[0];

    const int ntiles = (E + 15) >> 4;
    for (int tp = wave * 2; tp < ntiles; tp += nwaves * 2) {
        const int e0A = tp << 4;
        const bool haveB = (tp + 1) < ntiles;
        const int e0B = haveB ? ((tp + 1) << 4) : e0A;

        int erA = e0A + r; if (erA >= E) erA = E - 1;   // clamp; stores guarded
        int erB = e0B + r; if (erB >= E) erB = E - 1;

        const float4* fpA = (const float4*)(feats + (size_t)erA * DFEAT) + g * 2;
        const float4* fpB = (const float4*)(feats + (size_t)erB * DFEAT) + g * 2;

        // Issue ALL 16 loads before any compute — 16 KB in flight per wave.
        float4 a0 = fpA[0],  a1 = fpA[1];
        float4 a2 = fpA[8],  a3 = fpA[9];
        float4 a4 = fpA[16], a5 = fpA[17];
        float4 a6 = fpA[24], a7 = fpA[25];
        float4 q0 = fpB[0],  q1 = fpB[1];
        float4 q2 = fpB[8],  q3 = fpB[9];
        float4 q4 = fpB[16], q5 = fpB[17];
        float4 q6 = fpB[24], q7 = fpB[25];

        TILE_COMPUTE(a0, a1, a2, a3, a4, a5, a6, a7, e0A);
        if (haveB) TILE_COMPUTE(q0, q1, q2, q3, q4, q5, q6, q7, e0B);
    }
}

// Kernel B: scatter-mean inputs via sorted-run segmented reduction — round-6
// version (proven). ~2 atomics per center-run; correct even if unsorted.
__global__ __launch_bounds__(256) void bias_kernel(
    const void* __restrict__ eidx,
    const float* __restrict__ mag,
    float* __restrict__ csum,
    float* __restrict__ ccnt,
    const unsigned int* __restrict__ flag_any,
    int E)
{
    __shared__ int cs[256];
    __shared__ float ms[256];
    const int is64 = (flag_any[0] == 0u) ? 1 : 0;
    const int tloc = threadIdx.x;
    const int i = blockIdx.x * 256 + tloc;
    int c = -1; float m = 0.0f;
    if (i < E) { c = load_idx(eidx, is64, i); m = mag[i]; }
    cs[tloc] = c; ms[tloc] = m;
    __syncthreads();
    if (i < E) {
        bool leader = (tloc == 0) || (cs[tloc - 1] != c);
        if (leader) {
            float s = 0.0f; int n = 0; int j = tloc;
            int lim = min(256, E - blockIdx.x * 256);
            while (j < lim && cs[j] == c) { s += ms[j]; ++n; ++j; }
            atomicAdd(&csum[c], s);
            atomicAdd(&ccnt[c], (float)n);
        }
    }
}

// Kernel C: hash-join pairing (replaces argsort). KEY EXACTNESS INVARIANT:
// key arithmetic is BITWISE identical to the reference (f32 division vec/l,
// fabs, (x+y)+z, 1e10f mult, trunc). The two directed copies of an undirected
// edge have vec[j] == -vec[i] and len[j] == len[i] bitwise, so keys match
// exactly and the partner's unit vector is EXACTLY -u (proven round 9).
// Finisher debiases both, averages, and writes BOTH edges' force vectors to
// non-atomic fscratch (own edge coalesced, partner scattered; each edge
// written exactly once). Race-free CAS join: both partners walk the same
// probe sequence; slots never empty.
__global__ __launch_bounds__(256) void pair_kernel(
    const float* __restrict__ vec,
    const float* __restrict__ len,
    const void* __restrict__ eidx,
    const float* __restrict__ mag,
    const float* __restrict__ csum,
    const float* __restrict__ ccnt,
    unsigned long long* __restrict__ tab,
    float* __restrict__ fscr,
    const unsigned int* __restrict__ flag_any,
    int E, int hash_bits)
{
    int i = blockIdx.x * blockDim.x + threadIdx.x;
    if (i >= E) return;
    const int is64 = (flag_any[0] == 0u) ? 1 : 0;

    float l = len[i];
    float ux = vec[3 * i + 0] / l;     // IEEE division — matches reference bitwise
    float uy = vec[3 * i + 1] / l;
    float uz = vec[3 * i + 2] / l;
    float s3 = (fabsf(ux) + fabsf(uy)) + fabsf(uz);

    int ci_ = load_idx(eidx, is64, i);
    int ni_ = load_idx(eidx, is64, (long long)E + i);

    long long key = (long long)ci_ + (long long)ni_
                  + (long long)(1.0e10f * l)
                  + (long long)(1.0e10f * s3);

    unsigned long long entry = ((unsigned long long)key << IDX_BITS) | (unsigned)i;
    unsigned long long h = (unsigned long long)key * 0x9E3779B97F4A7C15ull;
    unsigned slot = (unsigned)(h >> (64 - hash_bits));
    const unsigned smask = (1u << hash_bits) - 1u;

    int j;
    while (true) {
        unsigned long long old = atomicCAS(&tab[slot], EMPTY_SLOT, entry);
        if (old == EMPTY_SLOT) return;  // first arrival: partner finishes the job
        if ((old >> IDX_BITS) == (unsigned long long)key) {
            j = (int)(old & IDX_MASK);
            break;
        }
        slot = (slot + 1) & smask;
    }

    int cj_ = load_idx(eidx, is64, j);
    float bi = csum[ci_] / fmaxf(ccnt[ci_], 1.0f);
    float bj = csum[cj_] / fmaxf(ccnt[cj_], 1.0f);
    float avg = 0.5f * ((mag[i] - bi) + (mag[j] - bj));

    float fx = avg * ux, fy = avg * uy, fz = avg * uz;
    fscr[3 * i + 0] = fx;   fscr[3 * i + 1] = fy;   fscr[3 * i + 2] = fz;
    fscr[3 * j + 0] = -fx;  fscr[3 * j + 1] = -fy;  fscr[3 * j + 2] = -fz;
}

// Kernel D: segment-sum of fscratch by (sorted) center via run detection;
// ~3 atomics per run. No vec/len/mag re-read, no divisions (moved to pair).
__global__ __launch_bounds__(256) void force_kernel(
    const float* __restrict__ fscr,
    const void* __restrict__ eidx,
    float* __restrict__ out,
    const unsigned int* __restrict__ flag_any,
    int E)
{
    __shared__ int cs[256];
    __shared__ float fx[256], fy[256], fz[256];
    const int is64 = (flag_any[0] == 0u) ? 1 : 0;
    const int tloc = threadIdx.x;
    const int i = blockIdx.x * 256 + tloc;
    int c = -1;
    if (i < E) {
        c = load_idx(eidx, is64, i);
        fx[tloc] = fscr[3 * i + 0];
        fy[tloc] = fscr[3 * i + 1];
        fz[tloc] = fscr[3 * i + 2];
    }
    cs[tloc] = c;
    __syncthreads();
    if (i < E) {
        bool leader = (tloc == 0) || (cs[tloc - 1] != c);
        if (leader) {
            float sx = 0.f, sy = 0.f, sz = 0.f;
            int j = tloc;
            int lim = min(256, E - blockIdx.x * 256);
            while (j < lim && cs[j] == c) { sx += fx[j]; sy += fy[j]; sz += fz[j]; ++j; }
            atomicAdd(&out[c * 3 + 0], sx);
            atomicAdd(&out[c * 3 + 1], sy);
            atomicAdd(&out[c * 3 + 2], sz);
        }
    }
}

extern "C" void kernel_launch(void* const* d_in, const int* in_sizes, int n_in,
                              void* d_out, int out_size, void* d_ws, size_t ws_size,
                              hipStream_t stream) {
    const float* feats = (const float*)d_in[0];
    const float* vec   = (const float*)d_in[1];
    const float* len   = (const float*)d_in[2];
    const void*  eidx  = d_in[3];
    const float* w1 = (const float*)d_in[4];
    const float* b1 = (const float*)d_in[5];
    const float* w2 = (const float*)d_in[6];
    const float* b2 = (const float*)d_in[7];
    float* out = (float*)d_out;

    const int E = in_sizes[0] / DFEAT;
    const int N = out_size / 3;

    // Workspace: mag (E) | csum (N) | ccnt (N) | flag (256B) | fscr (3E) | tab
    char* ws = (char*)d_ws;
    size_t off_mag  = 0;
    size_t off_csum = (off_mag + (size_t)E * 4 + 255) & ~(size_t)255;
    size_t off_ccnt = off_csum + (size_t)N * 4;
    size_t off_flag = (off_ccnt + (size_t)N * 4 + 255) & ~(size_t)255;
    size_t off_fscr = off_flag + 256;
    size_t off_tab  = (off_fscr + (size_t)E * 12 + 255) & ~(size_t)255;

    float* mag     = (float*)(ws + off_mag);
    float* csum    = (float*)(ws + off_csum);
    float* ccnt    = (float*)(ws + off_ccnt);
    unsigned int* flag_any = (unsigned int*)(ws + off_flag);
    float* fscr    = (float*)(ws + off_fscr);

    int hash_bits = 21;
    while (hash_bits > 20 && off_tab + (8ull << hash_bits) > ws_size) --hash_bits;
    unsigned long long* tab = (unsigned long long*)(ws + off_tab);

    // one contiguous memset covers csum | ccnt | flag
    hipMemsetAsync(csum, 0, off_flag + 256 - off_csum, stream);
    hipMemsetAsync(tab, 0xFF, (size_t)8 << hash_bits, stream);
    hipMemsetAsync(out, 0, (size_t)out_size * 4, stream);

    int n_check = E < 1024 ? E : 1024;
    detect_idx_kernel<<<1, 256, 0, stream>>>((const unsigned int*)eidx, n_check, flag_any);

    mlp_mag_kernel<<<1024, 256, 0, stream>>>(feats, w1, b1, w2, b2, mag, E);

    int eblocks = (E + 255) / 256;
    bias_kernel<<<eblocks, 256, 0, stream>>>(eidx, mag, csum, ccnt, flag_any, E);
    pair_kernel<<<eblocks, 256, 0, stream>>>(vec, len, eidx, mag, csum, ccnt,
                                             tab, fscr, flag_any, E, hash_bits);
    force_kernel<<<eblocks, 256, 0, stream>>>(fscr, eidx, out, flag_any, E);
}

// Round 13
// 327.659 us; speedup vs baseline: 1.7795x; 1.0283x over previous
//
#include <hip/hip_runtime.h>

typedef __bf16 bf16x8 __attribute__((ext_vector_type(8)));
typedef float f32x4 __attribute__((ext_vector_type(4)));

#define DFEAT 128
#define HDIM 64
#define IDX_BITS 21
#define IDX_MASK ((1u << IDX_BITS) - 1)
#define EMPTY_SLOT 0xFFFFFFFFFFFFFFFFull

// fast shifted-softplus: log(1+e^x) - log2, via native v_exp_f32/v_log_f32
__device__ __forceinline__ float ssp_fast(float x) {
    float m = fmaxf(x, 0.0f);
    float t = __expf(-fabsf(x));
    return m + __logf(1.0f + t) - 0.69314718055994531f;
}

// edge_index may arrive as int32 (harness contract) or int64 (reference dtype).
// Detect at runtime: int64 layout has all-zero odd dwords (values < 2^31).
__global__ void detect_idx_kernel(const unsigned int* __restrict__ p, int n_check,
                                  unsigned int* __restrict__ flag_any) {
    unsigned int acc = 0;
    for (int i = threadIdx.x; i < n_check; i += blockDim.x)
        acc |= p[2 * i + 1];
    if (acc) atomicOr(flag_any, 1u);
}

__device__ __forceinline__ int load_idx(const void* p, int is64, long long i) {
    if (is64) return (int)((const long long*)p)[i];
    return ((const int*)p)[i];
}

// bf16 convert of 8 floats from two float4s — member access only, no casts.
#define CVT8H(P, Q, H) do { \
    H[0] = (__bf16)P.x; H[1] = (__bf16)P.y; H[2] = (__bf16)P.z; H[3] = (__bf16)P.w; \
    H[4] = (__bf16)Q.x; H[5] = (__bf16)Q.y; H[6] = (__bf16)Q.z; H[7] = (__bf16)Q.w; \
} while (0)

#define MF(A, B, C) __builtin_amdgcn_mfma_f32_16x16x32_bf16(A, B, C, 0, 0, 0)

// One K-chunk (32 of 128): convert A, 1 MFMA per N-tile (pure bf16; absmax
// 0.031 vs 0.1406 threshold, measured rounds 6/9/10/11).
#define KSTEP(P, Q, KT) do { \
    bf16x8 h, bh; \
    CVT8H(P, Q, h); \
    bh = hiTab[((KT)*4 + 0) * 64 + lane]; acc0 = MF(h, bh, acc0); \
    bh = hiTab[((KT)*4 + 1) * 64 + lane]; acc1 = MF(h, bh, acc1); \
    bh = hiTab[((KT)*4 + 2) * 64 + lane]; acc2 = MF(h, bh, acc2); \
    bh = hiTab[((KT)*4 + 3) * 64 + lane]; acc3 = MF(h, bh, acc3); \
} while (0)

// row-slice ssp + w2 dot + 16-lane reduce for C-row j (compile-time J).
#define REDJ(J, OUT) do { \
    float z0 = acc0[J] + b1v0, z1 = acc1[J] + b1v1; \
    float z2 = acc2[J] + b1v2, z3 = acc3[J] + b1v3; \
    float t = ssp_fast(z0) * w2v0 + ssp_fast(z1) * w2v1 \
            + ssp_fast(z2) * w2v2 + ssp_fast(z3) * w2v3; \
    t += __shfl_xor(t, 1); t += __shfl_xor(t, 2); \
    t += __shfl_xor(t, 4); t += __shfl_xor(t, 8); \
    OUT = t; \
} while (0)

// Kernel A: per-edge MLP via bf16 MFMA — round-6 structure (proven ~190 us).
// All per-tile state in NAMED registers (rule #20). W1 bf16 fragment table
// in 16 KB LDS (staged via a transient 32 KB raw copy).
__global__ __launch_bounds__(256, 4) void mlp_mag_kernel(
    const float* __restrict__ feats,
    const float* __restrict__ w1,
    const float* __restrict__ b1,
    const float* __restrict__ w2,
    const float* __restrict__ b2,
    float* __restrict__ mag_raw,
    int E)
{
    __shared__ __align__(16) unsigned char smem[32768];
    float* w1s = (float*)smem;                 // transient: raw w1 (32 KB)
    bf16x8* hiTab = (bf16x8*)smem;             // final: bf16 frags (16 KB)

    const int lane = threadIdx.x & 63;
    const int r = lane & 15;
    const int g = lane >> 4;
    const int wave = blockIdx.x * (blockDim.x >> 6) + (threadIdx.x >> 6);
    const int nwaves = gridDim.x * (blockDim.x >> 6);

    // Stage B fragment table in LDS (once per block).
    for (int idx = threadIdx.x; idx < DFEAT * HDIM / 4; idx += blockDim.x)
        ((float4*)w1s)[idx] = ((const float4*)w1)[idx];
    __syncthreads();
    {
        const int tkt = threadIdx.x >> 6;      // this thread builds frags for k-chunk tkt
        const int tl = threadIdx.x & 63;
        const int tg = tl >> 4, tr = tl & 15;
        float vals[4][8];
#pragma unroll
        for (int nt = 0; nt < 4; ++nt)
#pragma unroll
            for (int i = 0; i < 8; ++i)
                vals[nt][i] = w1s[(tkt * 32 + tg * 8 + i) * HDIM + nt * 16 + tr];
        __syncthreads();                        // done reading raw w1; safe to overwrite
#pragma unroll
        for (int nt = 0; nt < 4; ++nt) {
            bf16x8 h;
#pragma unroll
            for (int i = 0; i < 8; ++i) h[i] = (__bf16)vals[nt][i];
            hiTab[(tkt * 4 + nt) * 64 + tl] = h;
        }
        __syncthreads();
    }

    const float b1v0 = b1[0 * 16 + r], b1v1 = b1[1 * 16 + r];
    const float b1v2 = b1[2 * 16 + r], b1v3 = b1[3 * 16 + r];
    const float w2v0 = w2[0 * 16 + r], w2v1 = w2[1 * 16 + r];
    const float w2v2 = w2[2 * 16 + r], w2v3 = w2[3 * 16 + r];
    const float b2v = b2[0];

    const int ntiles = (E + 15) >> 4;
    for (int tile = wave; tile < ntiles; tile += nwaves) {
        const int e0 = tile << 4;
        int er = e0 + r;
        if (er >= E) er = E - 1;           // clamp: loads stay valid; store is guarded

        const float4* fp = (const float4*)(feats + (size_t)er * DFEAT) + g * 2;
        float4 p0 = fp[0],  p1 = fp[1];
        float4 p2 = fp[8],  p3 = fp[9];
        float4 p4 = fp[16], p5 = fp[17];
        float4 p6 = fp[24], p7 = fp[25];

        f32x4 acc0 = {0.f,0.f,0.f,0.f}, acc1 = {0.f,0.f,0.f,0.f};
        f32x4 acc2 = {0.f,0.f,0.f,0.f}, acc3 = {0.f,0.f,0.f,0.f};
        KSTEP(p0, p1, 0);
        KSTEP(p2, p3, 1);
        KSTEP(p4, p5, 2);
        KSTEP(p6, p7, 3);

        float s0, s1, s2, s3;
        REDJ(0, s0); REDJ(1, s1); REDJ(2, s2); REDJ(3, s3);

        if (r < 4) {
            int e = e0 + g * 4 + r;
            if (e < E) {
                // 4-way select by r without a runtime-indexed array (cndmask chain)
                float sel = (r == 0) ? s0 : (r == 1) ? s1 : (r == 2) ? s2 : s3;
                mag_raw[e] = sel + b2v;
            }
        }
    }
}

// Kernel B: scatter-mean sums via sorted-run segmented reduction — round-6
// version (proven). ~2 atomics per center-run; correct even if unsorted.
__global__ __launch_bounds__(256) void bias_kernel(
    const void* __restrict__ eidx,
    const float* __restrict__ mag,
    float* __restrict__ csum,
    float* __restrict__ ccnt,
    const unsigned int* __restrict__ flag_any,
    int E)
{
    __shared__ int cs[256];
    __shared__ float ms[256];
    const int is64 = (flag_any[0] == 0u) ? 1 : 0;
    const int tloc = threadIdx.x;
    const int i = blockIdx.x * 256 + tloc;
    int c = -1; float m = 0.0f;
    if (i < E) { c = load_idx(eidx, is64, i); m = mag[i]; }
    cs[tloc] = c; ms[tloc] = m;
    __syncthreads();
    if (i < E) {
        bool leader = (tloc == 0) || (cs[tloc - 1] != c);
        if (leader) {
            float s = 0.0f; int n = 0; int j = tloc;
            int lim = min(256, E - blockIdx.x * 256);
            while (j < lim && cs[j] == c) { s += ms[j]; ++n; ++j; }
            atomicAdd(&csum[c], s);
            atomicAdd(&ccnt[c], (float)n);
        }
    }
}

// Kernel B2: mprime[i] = mag[i] - bias[center[i]] — fully coalesced (~13 MB).
// Precomputing the debiased magnitude collapses the pair-finder's dependent
// random-load chain (eidx[j], mag[j], csum[cj], ccnt[cj]) to ONE load of
// mprime[j]. Wait-free — no cross-thread handshake (round 12's inline-payload
// spin deadlocked: never spin on data produced in a sibling divergent branch).
__global__ __launch_bounds__(256) void mprime_kernel(
    const void* __restrict__ eidx,
    const float* __restrict__ mag,
    const float* __restrict__ csum,
    const float* __restrict__ ccnt,
    float* __restrict__ mprime,
    const unsigned int* __restrict__ flag_any,
    int E)
{
    int i = blockIdx.x * blockDim.x + threadIdx.x;
    if (i >= E) return;
    const int is64 = (flag_any[0] == 0u) ? 1 : 0;
    int c = load_idx(eidx, is64, i);
    mprime[i] = mag[i] - csum[c] / fmaxf(ccnt[c], 1.0f);
}

// Kernel C: hash-join pairing (replaces argsort). KEY EXACTNESS INVARIANT:
// key arithmetic is BITWISE identical to the reference (f32 division vec/l,
// fabs, (x+y)+z, 1e10f mult, trunc) — the dataset's no-collision guarantee is
// defined w.r.t. reference keys. The two directed copies of an undirected
// edge have vec[j] == -vec[i] and len[j] == len[i] bitwise, so keys match
// exactly and the partner's unit vector is EXACTLY -u (proven round 9).
// Finder: avg = 0.5*(mprime[i] + mprime[j]) — ONE random load — then writes
// BOTH edges' forces to non-atomic fscr (each edge written exactly once).
// Race-free CAS join: both partners walk the same probe sequence; slots
// never empty; no spin-waits anywhere.
__global__ __launch_bounds__(256) void pair_kernel(
    const float* __restrict__ vec,
    const float* __restrict__ len,
    const void* __restrict__ eidx,
    const float* __restrict__ mprime,
    unsigned long long* __restrict__ tab,
    float* __restrict__ fscr,
    const unsigned int* __restrict__ flag_any,
    int E, int hash_bits)
{
    int i = blockIdx.x * blockDim.x + threadIdx.x;
    if (i >= E) return;
    const int is64 = (flag_any[0] == 0u) ? 1 : 0;

    float l = len[i];
    float ux = vec[3 * i + 0] / l;     // IEEE division — matches reference bitwise
    float uy = vec[3 * i + 1] / l;
    float uz = vec[3 * i + 2] / l;
    float s3 = (fabsf(ux) + fabsf(uy)) + fabsf(uz);

    int ci_ = load_idx(eidx, is64, i);
    int ni_ = load_idx(eidx, is64, (long long)E + i);

    long long key = (long long)ci_ + (long long)ni_
                  + (long long)(1.0e10f * l)
                  + (long long)(1.0e10f * s3);

    unsigned long long entry = ((unsigned long long)key << IDX_BITS) | (unsigned)i;
    unsigned long long h = (unsigned long long)key * 0x9E3779B97F4A7C15ull;
    unsigned slot = (unsigned)(h >> (64 - hash_bits));
    const unsigned smask = (1u << hash_bits) - 1u;

    int j;
    while (true) {
        unsigned long long old = atomicCAS(&tab[slot], EMPTY_SLOT, entry);
        if (old == EMPTY_SLOT) return;  // first arrival: partner finishes the job
        if ((old >> IDX_BITS) == (unsigned long long)key) {
            j = (int)(old & IDX_MASK);
            break;
        }
        slot = (slot + 1) & smask;
    }

    float avg = 0.5f * (mprime[i] + mprime[j]);
    float fx = avg * ux, fy = avg * uy, fz = avg * uz;
    fscr[3 * i + 0] = fx;   fscr[3 * i + 1] = fy;   fscr[3 * i + 2] = fz;
    fscr[3 * j + 0] = -fx;  fscr[3 * j + 1] = -fy;  fscr[3 * j + 2] = -fz;
}

// Kernel D: segment-sum of fscratch by (sorted) center via run detection;
// ~3 atomics per run. No vec/len/mag re-read, no divisions.
__global__ __launch_bounds__(256) void force_kernel(
    const float* __restrict__ fscr,
    const void* __restrict__ eidx,
    float* __restrict__ out,
    const unsigned int* __restrict__ flag_any,
    int E)
{
    __shared__ int cs[256];
    __shared__ float fx[256], fy[256], fz[256];
    const int is64 = (flag_any[0] == 0u) ? 1 : 0;
    const int tloc = threadIdx.x;
    const int i = blockIdx.x * 256 + tloc;
    int c = -1;
    if (i < E) {
        c = load_idx(eidx, is64, i);
        fx[tloc] = fscr[3 * i + 0];
        fy[tloc] = fscr[3 * i + 1];
        fz[tloc] = fscr[3 * i + 2];
    }
    cs[tloc] = c;
    __syncthreads();
    if (i < E) {
        bool leader = (tloc == 0) || (cs[tloc - 1] != c);
        if (leader) {
            float sx = 0.f, sy = 0.f, sz = 0.f;
            int j = tloc;
            int lim = min(256, E - blockIdx.x * 256);
            while (j < lim && cs[j] == c) { sx += fx[j]; sy += fy[j]; sz += fz[j]; ++j; }
            atomicAdd(&out[c * 3 + 0], sx);
            atomicAdd(&out[c * 3 + 1], sy);
            atomicAdd(&out[c * 3 + 2], sz);
        }
    }
}

extern "C" void kernel_launch(void* const* d_in, const int* in_sizes, int n_in,
                              void* d_out, int out_size, void* d_ws, size_t ws_size,
                              hipStream_t stream) {
    const float* feats = (const float*)d_in[0];
    const float* vec   = (const float*)d_in[1];
    const float* len   = (const float*)d_in[2];
    const void*  eidx  = d_in[3];
    const float* w1 = (const float*)d_in[4];
    const float* b1 = (const float*)d_in[5];
    const float* w2 = (const float*)d_in[6];
    const float* b2 = (const float*)d_in[7];
    float* out = (float*)d_out;

    const int E = in_sizes[0] / DFEAT;
    const int N = out_size / 3;

    // Workspace: mag(E) | csum(N) | ccnt(N) | flag(256B) | mprime(E) | fscr(3E) | tab
    char* ws = (char*)d_ws;
    size_t off_mag  = 0;
    size_t off_csum = (off_mag + (size_t)E * 4 + 255) & ~(size_t)255;
    size_t off_ccnt = off_csum + (size_t)N * 4;
    size_t off_flag = (off_ccnt + (size_t)N * 4 + 255) & ~(size_t)255;
    size_t off_mpr  = off_flag + 256;
    size_t off_fscr = (off_mpr + (size_t)E * 4 + 255) & ~(size_t)255;
    size_t off_tab  = (off_fscr + (size_t)E * 12 + 255) & ~(size_t)255;

    float* mag     = (float*)(ws + off_mag);
    float* csum    = (float*)(ws + off_csum);
    float* ccnt    = (float*)(ws + off_ccnt);
    unsigned int* flag_any = (unsigned int*)(ws + off_flag);
    float* mprime  = (float*)(ws + off_mpr);
    float* fscr    = (float*)(ws + off_fscr);

    int hash_bits = 21;
    while (hash_bits > 20 && off_tab + (8ull << hash_bits) > ws_size) --hash_bits;
    unsigned long long* tab = (unsigned long long*)(ws + off_tab);

    // one contiguous memset covers csum | ccnt | flag
    hipMemsetAsync(csum, 0, off_flag + 256 - off_csum, stream);
    hipMemsetAsync(tab, 0xFF, (size_t)8 << hash_bits, stream);
    hipMemsetAsync(out, 0, (size_t)out_size * 4, stream);

    int n_check = E < 1024 ? E : 1024;
    detect_idx_kernel<<<1, 256, 0, stream>>>((const unsigned int*)eidx, n_check, flag_any);

    mlp_mag_kernel<<<1024, 256, 0, stream>>>(feats, w1, b1, w2, b2, mag, E);

    int eblocks = (E + 255) / 256;
    bias_kernel<<<eblocks, 256, 0, stream>>>(eidx, mag, csum, ccnt, flag_any, E);
    mprime_kernel<<<eblocks, 256, 0, stream>>>(eidx, mag, csum, ccnt, mprime, flag_any, E);
    pair_kernel<<<eblocks, 256, 0, stream>>>(vec, len, eidx, mprime,
                                             tab, fscr, flag_any, E, hash_bits);
    force_kernel<<<eblocks, 256, 0, stream>>>(fscr, eidx, out, flag_any, E);
}

// Round 14
// 304.670 us; speedup vs baseline: 1.9138x; 1.0755x over previous
//
#include <hip/hip_runtime.h>

typedef __bf16 bf16x8 __attribute__((ext_vector_type(8)));
typedef float f32x4 __attribute__((ext_vector_type(4)));
typedef unsigned long long u64x2 __attribute__((ext_vector_type(2)));

#define DFEAT 128
#define HDIM 64
#define IDX_BITS 21
#define IDX_MASK ((1u << IDX_BITS) - 1)
#define EMPTY_SLOT 0xFFFFFFFFFFFFFFFFull

// fast shifted-softplus: log(1+e^x) - log2, via native v_exp_f32/v_log_f32
__device__ __forceinline__ float ssp_fast(float x) {
    float m = fmaxf(x, 0.0f);
    float t = __expf(-fabsf(x));
    return m + __logf(1.0f + t) - 0.69314718055994531f;
}

// edge_index may arrive as int32 (harness contract) or int64 (reference dtype).
// Detect at runtime: int64 layout has all-zero odd dwords (values < 2^31).
__global__ void detect_idx_kernel(const unsigned int* __restrict__ p, int n_check,
                                  unsigned int* __restrict__ flag_any) {
    unsigned int acc = 0;
    for (int i = threadIdx.x; i < n_check; i += blockDim.x)
        acc |= p[2 * i + 1];
    if (acc) atomicOr(flag_any, 1u);
}

__device__ __forceinline__ int load_idx(const void* p, int is64, long long i) {
    if (is64) return (int)((const long long*)p)[i];
    return ((const int*)p)[i];
}

// bf16 convert of 8 floats from two f32x4s — static indices only.
#define CVT8H(P, Q, H) do { \
    H[0] = (__bf16)P[0]; H[1] = (__bf16)P[1]; H[2] = (__bf16)P[2]; H[3] = (__bf16)P[3]; \
    H[4] = (__bf16)Q[0]; H[5] = (__bf16)Q[1]; H[6] = (__bf16)Q[2]; H[7] = (__bf16)Q[3]; \
} while (0)

#define MF(A, B, C) __builtin_amdgcn_mfma_f32_16x16x32_bf16(A, B, C, 0, 0, 0)

// One K-chunk (32 of 128): convert A, 1 MFMA per N-tile (pure bf16; absmax
// 0.031 vs 0.1406 threshold, measured rounds 6/9/10/11/13).
#define KSTEP(P, Q, KT) do { \
    bf16x8 h, bh; \
    CVT8H(P, Q, h); \
    bh = hiTab[((KT)*4 + 0) * 64 + lane]; acc0 = MF(h, bh, acc0); \
    bh = hiTab[((KT)*4 + 1) * 64 + lane]; acc1 = MF(h, bh, acc1); \
    bh = hiTab[((KT)*4 + 2) * 64 + lane]; acc2 = MF(h, bh, acc2); \
    bh = hiTab[((KT)*4 + 3) * 64 + lane]; acc3 = MF(h, bh, acc3); \
} while (0)

// row-slice ssp + w2 dot + 16-lane reduce for C-row j (compile-time J).
#define REDJ(J, OUT) do { \
    float z0 = acc0[J] + b1v0, z1 = acc1[J] + b1v1; \
    float z2 = acc2[J] + b1v2, z3 = acc3[J] + b1v3; \
    float t = ssp_fast(z0) * w2v0 + ssp_fast(z1) * w2v1 \
            + ssp_fast(z2) * w2v2 + ssp_fast(z3) * w2v3; \
    t += __shfl_xor(t, 1); t += __shfl_xor(t, 2); \
    t += __shfl_xor(t, 4); t += __shfl_xor(t, 8); \
    OUT = t; \
} while (0)

// Kernel A: per-edge MLP via bf16 MFMA — round-6 structure (proven). Feature
// loads are NONTEMPORAL (zero reuse -> skip L2 allocation). All per-tile
// state in NAMED registers (rule #20). W1 bf16 fragment table in 16 KB LDS.
__global__ __launch_bounds__(256, 4) void mlp_mag_kernel(
    const float* __restrict__ feats,
    const float* __restrict__ w1,
    const float* __restrict__ b1,
    const float* __restrict__ w2,
    const float* __restrict__ b2,
    float* __restrict__ mag_raw,
    int E)
{
    __shared__ __align__(16) unsigned char smem[32768];
    float* w1s = (float*)smem;                 // transient: raw w1 (32 KB)
    bf16x8* hiTab = (bf16x8*)smem;             // final: bf16 frags (16 KB)

    const int lane = threadIdx.x & 63;
    const int r = lane & 15;
    const int g = lane >> 4;
    const int wave = blockIdx.x * (blockDim.x >> 6) + (threadIdx.x >> 6);
    const int nwaves = gridDim.x * (blockDim.x >> 6);

    // Stage B fragment table in LDS (once per block).
    for (int idx = threadIdx.x; idx < DFEAT * HDIM / 4; idx += blockDim.x)
        ((float4*)w1s)[idx] = ((const float4*)w1)[idx];
    __syncthreads();
    {
        const int tkt = threadIdx.x >> 6;      // this thread builds frags for k-chunk tkt
        const int tl = threadIdx.x & 63;
        const int tg = tl >> 4, tr = tl & 15;
        float vals[4][8];
#pragma unroll
        for (int nt = 0; nt < 4; ++nt)
#pragma unroll
            for (int i = 0; i < 8; ++i)
                vals[nt][i] = w1s[(tkt * 32 + tg * 8 + i) * HDIM + nt * 16 + tr];
        __syncthreads();                        // done reading raw w1; safe to overwrite
#pragma unroll
        for (int nt = 0; nt < 4; ++nt) {
            bf16x8 h;
#pragma unroll
            for (int i = 0; i < 8; ++i) h[i] = (__bf16)vals[nt][i];
            hiTab[(tkt * 4 + nt) * 64 + tl] = h;
        }
        __syncthreads();
    }

    const float b1v0 = b1[0 * 16 + r], b1v1 = b1[1 * 16 + r];
    const float b1v2 = b1[2 * 16 + r], b1v3 = b1[3 * 16 + r];
    const float w2v0 = w2[0 * 16 + r], w2v1 = w2[1 * 16 + r];
    const float w2v2 = w2[2 * 16 + r], w2v3 = w2[3 * 16 + r];
    const float b2v = b2[0];

    const int ntiles = (E + 15) >> 4;
    for (int tile = wave; tile < ntiles; tile += nwaves) {
        const int e0 = tile << 4;
        int er = e0 + r;
        if (er >= E) er = E - 1;           // clamp: loads stay valid; store is guarded

        const f32x4* fp = (const f32x4*)(feats + (size_t)er * DFEAT) + g * 2;
        f32x4 p0 = __builtin_nontemporal_load(fp + 0);
        f32x4 p1 = __builtin_nontemporal_load(fp + 1);
        f32x4 p2 = __builtin_nontemporal_load(fp + 8);
        f32x4 p3 = __builtin_nontemporal_load(fp + 9);
        f32x4 p4 = __builtin_nontemporal_load(fp + 16);
        f32x4 p5 = __builtin_nontemporal_load(fp + 17);
        f32x4 p6 = __builtin_nontemporal_load(fp + 24);
        f32x4 p7 = __builtin_nontemporal_load(fp + 25);

        f32x4 acc0 = {0.f,0.f,0.f,0.f}, acc1 = {0.f,0.f,0.f,0.f};
        f32x4 acc2 = {0.f,0.f,0.f,0.f}, acc3 = {0.f,0.f,0.f,0.f};
        KSTEP(p0, p1, 0);
        KSTEP(p2, p3, 1);
        KSTEP(p4, p5, 2);
        KSTEP(p6, p7, 3);

        float s0, s1, s2, s3;
        REDJ(0, s0); REDJ(1, s1); REDJ(2, s2); REDJ(3, s3);

        if (r < 4) {
            int e = e0 + g * 4 + r;
            if (e < E) {
                // 4-way select by r without a runtime-indexed array (cndmask chain)
                float sel = (r == 0) ? s0 : (r == 1) ? s1 : (r == 2) ? s2 : s3;
                mag_raw[e] = sel + b2v;
            }
        }
    }
}

// Kernel B: scatter-mean sums via sorted-run segmented reduction — round-6
// version (proven). ~2 atomics per center-run; correct even if unsorted.
__global__ __launch_bounds__(256) void bias_kernel(
    const void* __restrict__ eidx,
    const float* __restrict__ mag,
    float* __restrict__ csum,
    float* __restrict__ ccnt,
    const unsigned int* __restrict__ flag_any,
    int E)
{
    __shared__ int cs[256];
    __shared__ float ms[256];
    const int is64 = (flag_any[0] == 0u) ? 1 : 0;
    const int tloc = threadIdx.x;
    const int i = blockIdx.x * 256 + tloc;
    int c = -1; float m = 0.0f;
    if (i < E) { c = load_idx(eidx, is64, i); m = mag[i]; }
    cs[tloc] = c; ms[tloc] = m;
    __syncthreads();
    if (i < E) {
        bool leader = (tloc == 0) || (cs[tloc - 1] != c);
        if (leader) {
            float s = 0.0f; int n = 0; int j = tloc;
            int lim = min(256, E - blockIdx.x * 256);
            while (j < lim && cs[j] == c) { s += ms[j]; ++n; ++j; }
            atomicAdd(&csum[c], s);
            atomicAdd(&ccnt[c], (float)n);
        }
    }
}

// Shared key computation. KEY EXACTNESS INVARIANT: bitwise identical to the
// reference (f32 division vec/l, fabs, (x+y)+z, 1e10f mult, trunc) — the
// dataset's no-collision guarantee is defined w.r.t. reference keys.
__device__ __forceinline__ long long edge_key(const float* vec, float l,
                                              int i, int ci, int ni,
                                              float& ux, float& uy, float& uz) {
    ux = vec[3 * i + 0] / l;
    uy = vec[3 * i + 1] / l;
    uz = vec[3 * i + 2] / l;
    float s3 = (fabsf(ux) + fabsf(uy)) + fabsf(uz);
    return (long long)ci + (long long)ni
         + (long long)(1.0e10f * l)
         + (long long)(1.0e10f * s3);
}

// Kernel C1 (INSERT phase): edges with center<neigh (exactly one per
// undirected pair; no self-edges by construction) CAS-claim a 16-byte slot
// and plain-store their DEBIASED magnitude as the payload. No reader exists
// inside this kernel, so there is no handshake (round 12's intra-kernel
// spin deadlocked; the kernel boundary is the release point here).
// Inserter keys are all distinct -> no key-match check needed on collision.
__global__ __launch_bounds__(256) void insert_kernel(
    const float* __restrict__ vec,
    const float* __restrict__ len,
    const void* __restrict__ eidx,
    const float* __restrict__ mag,
    const float* __restrict__ csum,
    const float* __restrict__ ccnt,
    unsigned long long* __restrict__ tab,   // 2 qwords per slot
    const unsigned int* __restrict__ flag_any,
    int E, int hash_bits)
{
    int i = blockIdx.x * blockDim.x + threadIdx.x;
    if (i >= E) return;
    const int is64 = (flag_any[0] == 0u) ? 1 : 0;

    int ci_ = load_idx(eidx, is64, i);
    int ni_ = load_idx(eidx, is64, (long long)E + i);
    if (ci_ >= ni_) return;                 // finder role handles these

    float ux, uy, uz;
    long long key = edge_key(vec, len[i], i, ci_, ni_, ux, uy, uz);
    float mi = mag[i] - csum[ci_] / fmaxf(ccnt[ci_], 1.0f);

    unsigned long long entry = ((unsigned long long)key << IDX_BITS) | (unsigned)i;
    unsigned long long h = (unsigned long long)key * 0x9E3779B97F4A7C15ull;
    unsigned slot = (unsigned)(h >> (64 - hash_bits));
    const unsigned smask = (1u << hash_bits) - 1u;

    while (true) {
        unsigned long long old = atomicCAS(&tab[2 * (size_t)slot], EMPTY_SLOT, entry);
        if (old == EMPTY_SLOT) {
            *(unsigned int*)(tab + 2 * (size_t)slot + 1) = __float_as_uint(mi);
            return;
        }
        slot = (slot + 1) & smask;
    }
}

// Kernel C2 (FIND phase): edges with center>neigh probe with PLAIN 16-byte
// loads (no CAS). Linear-probing invariant: every slot from h(key) to the
// partner's slot was occupied when the partner inserted, and occupancy only
// grows -> the finder never meets EMPTY before its key. Key + partner index
// + partner payload arrive in ONE cache line. Partner's unit vector is
// EXACTLY -u (vec[j]==-vec[i], len[j]==len[i] bitwise; proven round 9):
// write both edges' forces to non-atomic fscr (each edge written once).
__global__ __launch_bounds__(256) void find_kernel(
    const float* __restrict__ vec,
    const float* __restrict__ len,
    const void* __restrict__ eidx,
    const float* __restrict__ mag,
    const float* __restrict__ csum,
    const float* __restrict__ ccnt,
    const unsigned long long* __restrict__ tab,
    float* __restrict__ fscr,
    const unsigned int* __restrict__ flag_any,
    int E, int hash_bits)
{
    int i = blockIdx.x * blockDim.x + threadIdx.x;
    if (i >= E) return;
    const int is64 = (flag_any[0] == 0u) ? 1 : 0;

    int ci_ = load_idx(eidx, is64, i);
    int ni_ = load_idx(eidx, is64, (long long)E + i);
    if (ci_ <= ni_) return;                 // inserter role handled these

    float ux, uy, uz;
    long long key = edge_key(vec, len[i], i, ci_, ni_, ux, uy, uz);
    float mi = mag[i] - csum[ci_] / fmaxf(ccnt[ci_], 1.0f);

    unsigned long long h = (unsigned long long)key * 0x9E3779B97F4A7C15ull;
    unsigned slot = (unsigned)(h >> (64 - hash_bits));
    const unsigned smask = (1u << hash_bits) - 1u;
    const u64x2* t2 = (const u64x2*)tab;

    int j = -1;
    float mj = 0.0f;
    int guard = (int)smask + 1;             // safety: surface error, never hang
    while (guard-- > 0) {
        u64x2 e = t2[slot];
        if ((e[0] >> IDX_BITS) == (unsigned long long)key) {
            j = (int)(e[0] & IDX_MASK);
            mj = __uint_as_float((unsigned int)(e[1] & 0xFFFFFFFFull));
            break;
        }
        slot = (slot + 1) & smask;
    }
    if (j < 0) return;                      // unreachable if invariants hold

    float avg = 0.5f * (mi + mj);
    float fx = avg * ux, fy = avg * uy, fz = avg * uz;
    fscr[3 * i + 0] = fx;   fscr[3 * i + 1] = fy;   fscr[3 * i + 2] = fz;
    fscr[3 * j + 0] = -fx;  fscr[3 * j + 1] = -fy;  fscr[3 * j + 2] = -fz;
}

// Kernel D: segment-sum of fscratch by (sorted) center via run detection;
// ~3 atomics per run (round-9 proved per-edge scattered atomics cost ~250us).
__global__ __launch_bounds__(256) void force_kernel(
    const float* __restrict__ fscr,
    const void* __restrict__ eidx,
    float* __restrict__ out,
    const unsigned int* __restrict__ flag_any,
    int E)
{
    __shared__ int cs[256];
    __shared__ float fx[256], fy[256], fz[256];
    const int is64 = (flag_any[0] == 0u) ? 1 : 0;
    const int tloc = threadIdx.x;
    const int i = blockIdx.x * 256 + tloc;
    int c = -1;
    if (i < E) {
        c = load_idx(eidx, is64, i);
        fx[tloc] = fscr[3 * i + 0];
        fy[tloc] = fscr[3 * i + 1];
        fz[tloc] = fscr[3 * i + 2];
    }
    cs[tloc] = c;
    __syncthreads();
    if (i < E) {
        bool leader = (tloc == 0) || (cs[tloc - 1] != c);
        if (leader) {
            float sx = 0.f, sy = 0.f, sz = 0.f;
            int j = tloc;
            int lim = min(256, E - blockIdx.x * 256);
            while (j < lim && cs[j] == c) { sx += fx[j]; sy += fy[j]; sz += fz[j]; ++j; }
            atomicAdd(&out[c * 3 + 0], sx);
            atomicAdd(&out[c * 3 + 1], sy);
            atomicAdd(&out[c * 3 + 2], sz);
        }
    }
}

extern "C" void kernel_launch(void* const* d_in, const int* in_sizes, int n_in,
                              void* d_out, int out_size, void* d_ws, size_t ws_size,
                              hipStream_t stream) {
    const float* feats = (const float*)d_in[0];
    const float* vec   = (const float*)d_in[1];
    const float* len   = (const float*)d_in[2];
    const void*  eidx  = d_in[3];
    const float* w1 = (const float*)d_in[4];
    const float* b1 = (const float*)d_in[5];
    const float* w2 = (const float*)d_in[6];
    const float* b2 = (const float*)d_in[7];
    float* out = (float*)d_out;

    const int E = in_sizes[0] / DFEAT;
    const int N = out_size / 3;

    // Workspace: mag(E) | csum(N) | ccnt(N) | flag(256B) | fscr(3E) | tab(16B/slot)
    char* ws = (char*)d_ws;
    size_t off_mag  = 0;
    size_t off_csum = (off_mag + (size_t)E * 4 + 255) & ~(size_t)255;
    size_t off_ccnt = off_csum + (size_t)N * 4;
    size_t off_flag = (off_ccnt + (size_t)N * 4 + 255) & ~(size_t)255;
    size_t off_fscr = off_flag + 256;
    size_t off_tab  = (off_fscr + (size_t)E * 12 + 255) & ~(size_t)255;

    float* mag     = (float*)(ws + off_mag);
    float* csum    = (float*)(ws + off_csum);
    float* ccnt    = (float*)(ws + off_ccnt);
    unsigned int* flag_any = (unsigned int*)(ws + off_flag);
    float* fscr    = (float*)(ws + off_fscr);

    int hash_bits = 21;                 // 16B entries, 800K inserts -> 38% load
    while (hash_bits > 20 && off_tab + (16ull << hash_bits) > ws_size) --hash_bits;
    unsigned long long* tab = (unsigned long long*)(ws + off_tab);

    // one contiguous memset covers csum | ccnt | flag
    hipMemsetAsync(csum, 0, off_flag + 256 - off_csum, stream);
    hipMemsetAsync(tab, 0xFF, (size_t)16 << hash_bits, stream);
    hipMemsetAsync(out, 0, (size_t)out_size * 4, stream);

    int n_check = E < 1024 ? E : 1024;
    detect_idx_kernel<<<1, 256, 0, stream>>>((const unsigned int*)eidx, n_check, flag_any);

    mlp_mag_kernel<<<1024, 256, 0, stream>>>(feats, w1, b1, w2, b2, mag, E);

    int eblocks = (E + 255) / 256;
    bias_kernel<<<eblocks, 256, 0, stream>>>(eidx, mag, csum, ccnt, flag_any, E);
    insert_kernel<<<eblocks, 256, 0, stream>>>(vec, len, eidx, mag, csum, ccnt,
                                               tab, flag_any, E, hash_bits);
    find_kernel<<<eblocks, 256, 0, stream>>>(vec, len, eidx, mag, csum, ccnt,
                                             tab, fscr, flag_any, E, hash_bits);
    force_kernel<<<eblocks, 256, 0, stream>>>(fscr, eidx, out, flag_any, E);
}